// Round 1
// baseline (499.175 us; speedup 1.0000x reference)
//
#include <hip/hip_runtime.h>
#include <hip/hip_bf16.h>

#define B_ 2
#define N_ 1024
#define D_ 768
#define E_ 128
#define H_ 16
#define HD_ 48
#define HDP_ 64

typedef short bf16x8 __attribute__((ext_vector_type(8)));
typedef float f32x4 __attribute__((ext_vector_type(4)));

__device__ __forceinline__ unsigned short f2bf(float f) {
    unsigned int u = __float_as_uint(f);
    u += 0x7fffu + ((u >> 16) & 1u);
    return (unsigned short)(u >> 16);
}
__device__ __forceinline__ float bf2f(unsigned short s) {
    return __uint_as_float(((unsigned int)s) << 16);
}

// load 8 consecutive fp32, convert to bf16 fragment
__device__ __forceinline__ bf16x8 ld_frag_f32(const float* __restrict__ p) {
    float4 a = *(const float4*)p;
    float4 b = *(const float4*)(p + 4);
    bf16x8 r;
    r[0] = (short)f2bf(a.x); r[1] = (short)f2bf(a.y);
    r[2] = (short)f2bf(a.z); r[3] = (short)f2bf(a.w);
    r[4] = (short)f2bf(b.x); r[5] = (short)f2bf(b.y);
    r[6] = (short)f2bf(b.z); r[7] = (short)f2bf(b.w);
    return r;
}

// ---------------------------------------------------------------------------
// Kernel 1: projections.  z=0: q=node@Wq.T+bq -> qp (b,h,n,64) bf16 (pad 0)
//                         z=1: k=kin @Wk.T    -> kp  same layout
//                         z=2: v^T = Wv@kin^T -> vT (b,h,48,n) bf16
//                         z=3: g=sigmoid(node@Wg.T) -> g (b,n,768) f32
// block 256 = 4 waves (2x2), wave tile 32x32, K-loop 32.
// ---------------------------------------------------------------------------
__global__ __launch_bounds__(256) void proj_kernel(
    const float* __restrict__ node, const float* __restrict__ kin,
    const float* __restrict__ Wq, const float* __restrict__ bq,
    const float* __restrict__ Wk, const float* __restrict__ Wv,
    const float* __restrict__ Wg,
    unsigned short* __restrict__ qp, unsigned short* __restrict__ kp,
    unsigned short* __restrict__ vT, float* __restrict__ g)
{
    const int z = blockIdx.z;
    const int lane = threadIdx.x & 63;
    const int w = threadIdx.x >> 6;
    const int wm = w >> 1, wn = w & 1;
    const int lr = lane & 15, lg = lane >> 4;

    const float* A;
    const float* Wm;
    int mbase, nbase;
    if (z == 2) {                    // C[d][tok] = Wv * kin^T
        A = Wv; Wm = kin;
        mbase = blockIdx.y * 64 + wm * 32;   // d rows (768)
        nbase = blockIdx.x * 64 + wn * 32;   // tok cols (2048)
    } else {
        A = (z == 1) ? kin : node;
        Wm = (z == 0) ? Wq : (z == 1) ? Wk : Wg;
        mbase = blockIdx.x * 64 + wm * 32;   // tok rows (2048)
        nbase = blockIdx.y * 64 + wn * 32;   // d cols (768)
    }

    f32x4 acc[2][2] = {};
    for (int k0 = 0; k0 < D_; k0 += 32) {
        bf16x8 af[2], bfm[2];
#pragma unroll
        for (int ms = 0; ms < 2; ++ms)
            af[ms] = ld_frag_f32(A + (size_t)(mbase + ms * 16 + lr) * D_ + k0 + lg * 8);
#pragma unroll
        for (int ns = 0; ns < 2; ++ns)
            bfm[ns] = ld_frag_f32(Wm + (size_t)(nbase + ns * 16 + lr) * D_ + k0 + lg * 8);
#pragma unroll
        for (int ms = 0; ms < 2; ++ms)
#pragma unroll
            for (int ns = 0; ns < 2; ++ns)
                acc[ms][ns] = __builtin_amdgcn_mfma_f32_16x16x32_bf16(
                    af[ms], bfm[ns], acc[ms][ns], 0, 0, 0);
    }

#pragma unroll
    for (int ms = 0; ms < 2; ++ms) {
#pragma unroll
        for (int ns = 0; ns < 2; ++ns) {
#pragma unroll
            for (int r = 0; r < 4; ++r) {
                const int row = mbase + ms * 16 + lg * 4 + r;
                const int col = nbase + ns * 16 + lr;
                float v = acc[ms][ns][r];
                if (z == 0) {
                    v += bq[col];
                    const int b = row >> 10, tok = row & 1023;
                    const int h = col / HD_, hd = col - h * HD_;
                    qp[((size_t)((b * H_ + h) * N_ + tok) << 6) + hd] = f2bf(v);
                } else if (z == 1) {
                    const int b = row >> 10, tok = row & 1023;
                    const int h = col / HD_, hd = col - h * HD_;
                    kp[((size_t)((b * H_ + h) * N_ + tok) << 6) + hd] = f2bf(v);
                } else if (z == 3) {
                    g[(size_t)row * D_ + col] = 1.f / (1.f + __expf(-v));
                } else {  // z==2: row = d, col = tok
                    const int b = col >> 10, tok = col & 1023;
                    const int h = row / HD_, hd = row - h * HD_;
                    vT[((size_t)((b * H_ + h) * HD_ + hd) << 10) + tok] = f2bf(v);
                }
            }
        }
    }
}

// ---------------------------------------------------------------------------
// Kernel 2: pair bias.  bias[b,h,i,j] = LN_E(edge[b,i,j,:]) @ Wz   (bf16 out)
// block 256 = 4 waves, 64 rows/block (row = (b,i,j) linear), 1 MFMA chain/wave.
// ---------------------------------------------------------------------------
__global__ __launch_bounds__(256) void bias_kernel(
    const float* __restrict__ edge, const float* __restrict__ lng,
    const float* __restrict__ lnb, const float* __restrict__ Wz,
    unsigned short* __restrict__ bias)
{
    const int lane = threadIdx.x & 63;
    const int w = threadIdx.x >> 6;
    const int lr = lane & 15, lg = lane >> 4;
    const size_t row0 = (size_t)blockIdx.x * 64;
    const int local = w * 16 + lr;
    const float* rp = edge + (row0 + local) * E_;

    // loop-invariant Wz B-fragments: B[k=e][col=h]
    bf16x8 wzf[4];
#pragma unroll
    for (int ks = 0; ks < 4; ++ks) {
#pragma unroll
        for (int e = 0; e < 8; ++e) {
            const int ee = ks * 32 + lg * 8 + e;
            wzf[ks][e] = (short)f2bf(Wz[ee * H_ + lr]);
        }
    }

    float x[4][8];
    float s = 0.f, sq = 0.f;
#pragma unroll
    for (int ks = 0; ks < 4; ++ks) {
        float4 a = *(const float4*)(rp + ks * 32 + lg * 8);
        float4 b = *(const float4*)(rp + ks * 32 + lg * 8 + 4);
        x[ks][0] = a.x; x[ks][1] = a.y; x[ks][2] = a.z; x[ks][3] = a.w;
        x[ks][4] = b.x; x[ks][5] = b.y; x[ks][6] = b.z; x[ks][7] = b.w;
#pragma unroll
        for (int e = 0; e < 8; ++e) { s += x[ks][e]; sq = fmaf(x[ks][e], x[ks][e], sq); }
    }
    s  += __shfl_xor(s, 16);  s  += __shfl_xor(s, 32);
    sq += __shfl_xor(sq, 16); sq += __shfl_xor(sq, 32);
    const float mean = s * (1.f / 128.f);
    const float var = sq * (1.f / 128.f) - mean * mean;
    const float rs = rsqrtf(var + 1e-5f);
    const float c0 = -mean * rs;

    f32x4 acc = {};
#pragma unroll
    for (int ks = 0; ks < 4; ++ks) {
        bf16x8 af;
#pragma unroll
        for (int e = 0; e < 8; ++e) {
            const int ee = ks * 32 + lg * 8 + e;
            const float zn = fmaf(fmaf(x[ks][e], rs, c0), lng[ee], lnb[ee]);
            af[e] = (short)f2bf(zn);
        }
        acc = __builtin_amdgcn_mfma_f32_16x16x32_bf16(af, wzf[ks], acc, 0, 0, 0);
    }

    // transpose in LDS for coalesced global writes. C: col(lr)=h, row=lg*4+r
    __shared__ unsigned short tile[16][64];
#pragma unroll
    for (int r = 0; r < 4; ++r)
        tile[lr][w * 16 + lg * 4 + r] = f2bf(acc[r]);
    __syncthreads();

    const int t = threadIdx.x;
    const int h = t >> 4, c = (t & 15) * 4;
    const int b = (int)(row0 >> 20);
    const int i = (int)((row0 >> 10) & 1023);
    const int j0 = (int)(row0 & 1023);
    ushort4 v4 = *(const ushort4*)&tile[h][c];
    *(ushort4*)(bias + (((size_t)((b * H_ + h) * N_ + i)) << 10) + j0 + c) = v4;
}

// ---------------------------------------------------------------------------
// Kernel 3: flash attention. 1 wave per (b,h, 16 i-rows); j streamed in 32s.
// S = q k^T * scale + bias + mask ; online softmax ; O += P V (P via LDS).
// ---------------------------------------------------------------------------
__global__ __launch_bounds__(64) void attn_kernel(
    const unsigned short* __restrict__ qp, const unsigned short* __restrict__ kp,
    const unsigned short* __restrict__ vT, const unsigned short* __restrict__ bias,
    const int* __restrict__ mask, float* __restrict__ o)
{
    const int lane = threadIdx.x & 63;
    const int lr = lane & 15, lg = lane >> 4;
    const int bh = blockIdx.x >> 6;    // 0..31
    const int it = blockIdx.x & 63;    // 0..63
    const int b = bh >> 4;
    const int h = bh & 15;
    const int i0 = it * 16;
    const float scale = 0.14433756729740643f;  // 1/sqrt(48)

    bf16x8 qf[2];
    {
        const unsigned short* qb = qp + (((size_t)bh * N_ + i0 + lr) << 6) + lg * 8;
        qf[0] = *(const bf16x8*)qb;
        qf[1] = *(const bf16x8*)(qb + 32);
    }

    float m[4], li[4];
#pragma unroll
    for (int r = 0; r < 4; ++r) { m[r] = -1e30f; li[r] = 0.f; }
    f32x4 ov[3] = {};

    __shared__ unsigned short pt[16][40];   // P tile, padded stride (80B)

    for (int j0 = 0; j0 < N_; j0 += 32) {
        float p[2][4];
#pragma unroll
        for (int s = 0; s < 2; ++s) {
            const unsigned short* kb =
                kp + (((size_t)bh * N_ + j0 + s * 16 + lr) << 6) + lg * 8;
            bf16x8 k0f = *(const bf16x8*)kb;
            bf16x8 k1f = *(const bf16x8*)(kb + 32);
            f32x4 t = {};
            t = __builtin_amdgcn_mfma_f32_16x16x32_bf16(qf[0], k0f, t, 0, 0, 0);
            t = __builtin_amdgcn_mfma_f32_16x16x32_bf16(qf[1], k1f, t, 0, 0, 0);
            const int j = j0 + s * 16 + lr;
            const float mk = (1.f - (float)mask[b * N_ + j]) * (-1.0e6f);
#pragma unroll
            for (int r = 0; r < 4; ++r) {
                const float bv =
                    bf2f(bias[(((size_t)bh * N_ + i0 + lg * 4 + r) << 10) + j]);
                p[s][r] = fmaf(t[r], scale, bv + mk);
            }
        }
        // row max over j (16 lanes x 2 frags)
        float tm[4];
#pragma unroll
        for (int r = 0; r < 4; ++r) tm[r] = fmaxf(p[0][r], p[1][r]);
#pragma unroll
        for (int d = 1; d < 16; d <<= 1)
#pragma unroll
            for (int r = 0; r < 4; ++r) tm[r] = fmaxf(tm[r], __shfl_xor(tm[r], d));

        float alpha[4];
#pragma unroll
        for (int r = 0; r < 4; ++r) {
            const float mn = fmaxf(m[r], tm[r]);
            alpha[r] = __expf(m[r] - mn);
            m[r] = mn;
        }
        float rsum[4];
#pragma unroll
        for (int r = 0; r < 4; ++r) {
            p[0][r] = __expf(p[0][r] - m[r]);
            p[1][r] = __expf(p[1][r] - m[r]);
            rsum[r] = p[0][r] + p[1][r];
        }
#pragma unroll
        for (int d = 1; d < 16; d <<= 1)
#pragma unroll
            for (int r = 0; r < 4; ++r) rsum[r] += __shfl_xor(rsum[r], d);
#pragma unroll
        for (int r = 0; r < 4; ++r) li[r] = li[r] * alpha[r] + rsum[r];
#pragma unroll
        for (int v = 0; v < 3; ++v)
#pragma unroll
            for (int r = 0; r < 4; ++r) ov[v][r] *= alpha[r];

        // P -> LDS (C layout) -> A fragment
#pragma unroll
        for (int s = 0; s < 2; ++s)
#pragma unroll
            for (int r = 0; r < 4; ++r)
                pt[lg * 4 + r][s * 16 + lr] = f2bf(p[s][r]);
        __syncthreads();
        bf16x8 pa = *(const bf16x8*)&pt[lr][lg * 8];

#pragma unroll
        for (int v = 0; v < 3; ++v) {
            const unsigned short* vb =
                vT + (((size_t)(bh * HD_ + v * 16 + lr)) << 10) + j0 + lg * 8;
            bf16x8 vf = *(const bf16x8*)vb;
            ov[v] = __builtin_amdgcn_mfma_f32_16x16x32_bf16(pa, vf, ov[v], 0, 0, 0);
        }
        __syncthreads();
    }

#pragma unroll
    for (int v = 0; v < 3; ++v)
#pragma unroll
        for (int r = 0; r < 4; ++r) {
            const float val = ov[v][r] / li[r];
            o[(size_t)(b * N_ + i0 + lg * 4 + r) * D_ + h * HD_ + v * 16 + lr] = val;
        }
}

// ---------------------------------------------------------------------------
// Kernel 4: prep for split-bf16 final GEMM. y=0: X=g*o -> hi/lo. y=1: Wo -> hi/lo.
// ---------------------------------------------------------------------------
__global__ void prep_kernel(const float* __restrict__ g, const float* __restrict__ o,
                            const float* __restrict__ Wo,
                            unsigned short* __restrict__ Xhi, unsigned short* __restrict__ Xlo,
                            unsigned short* __restrict__ Whi, unsigned short* __restrict__ Wlo)
{
    const int idx = blockIdx.x * 256 + threadIdx.x;
    if (blockIdx.y == 0) {
        if (idx < B_ * N_ * D_) {
            const float xv = g[idx] * o[idx];
            const unsigned short hi = f2bf(xv);
            Xhi[idx] = hi;
            Xlo[idx] = f2bf(xv - bf2f(hi));
        }
    } else {
        if (idx < D_ * D_) {
            const float xv = Wo[idx];
            const unsigned short hi = f2bf(xv);
            Whi[idx] = hi;
            Wlo[idx] = f2bf(xv - bf2f(hi));
        }
    }
}

// ---------------------------------------------------------------------------
// Kernel 5: out = X @ Wo.T via split-bf16 (3 MFMA: hi*hi + hi*lo + lo*hi)
// ---------------------------------------------------------------------------
__global__ __launch_bounds__(256) void out_gemm(
    const unsigned short* __restrict__ Xhi, const unsigned short* __restrict__ Xlo,
    const unsigned short* __restrict__ Whi, const unsigned short* __restrict__ Wlo,
    float* __restrict__ out)
{
    const int lane = threadIdx.x & 63;
    const int w = threadIdx.x >> 6;
    const int wm = w >> 1, wn = w & 1;
    const int lr = lane & 15, lg = lane >> 4;
    const int mbase = blockIdx.x * 64 + wm * 32;
    const int nbase = blockIdx.y * 64 + wn * 32;

    f32x4 acc[2][2] = {};
    for (int k0 = 0; k0 < D_; k0 += 32) {
        bf16x8 ah[2], al[2], bh[2], bl[2];
#pragma unroll
        for (int ms = 0; ms < 2; ++ms) {
            const size_t off = (size_t)(mbase + ms * 16 + lr) * D_ + k0 + lg * 8;
            ah[ms] = *(const bf16x8*)(Xhi + off);
            al[ms] = *(const bf16x8*)(Xlo + off);
        }
#pragma unroll
        for (int ns = 0; ns < 2; ++ns) {
            const size_t off = (size_t)(nbase + ns * 16 + lr) * D_ + k0 + lg * 8;
            bh[ns] = *(const bf16x8*)(Whi + off);
            bl[ns] = *(const bf16x8*)(Wlo + off);
        }
#pragma unroll
        for (int ms = 0; ms < 2; ++ms)
#pragma unroll
            for (int ns = 0; ns < 2; ++ns) {
                acc[ms][ns] = __builtin_amdgcn_mfma_f32_16x16x32_bf16(ah[ms], bh[ns], acc[ms][ns], 0, 0, 0);
                acc[ms][ns] = __builtin_amdgcn_mfma_f32_16x16x32_bf16(ah[ms], bl[ns], acc[ms][ns], 0, 0, 0);
                acc[ms][ns] = __builtin_amdgcn_mfma_f32_16x16x32_bf16(al[ms], bh[ns], acc[ms][ns], 0, 0, 0);
            }
    }
#pragma unroll
    for (int ms = 0; ms < 2; ++ms)
#pragma unroll
        for (int ns = 0; ns < 2; ++ns)
#pragma unroll
            for (int r = 0; r < 4; ++r)
                out[(size_t)(mbase + ms * 16 + lg * 4 + r) * D_ + nbase + ns * 16 + lr] =
                    acc[ms][ns][r];
}

// ---------------------------------------------------------------------------
extern "C" void kernel_launch(void* const* d_in, const int* in_sizes, int n_in,
                              void* d_out, int out_size, void* d_ws, size_t ws_size,
                              hipStream_t stream) {
    const float* node = (const float*)d_in[0];
    const float* edge = (const float*)d_in[1];
    const int*   mask = (const int*)d_in[2];
    const float* kin  = (const float*)d_in[3];
    const float* Wq   = (const float*)d_in[4];
    const float* bq   = (const float*)d_in[5];
    const float* Wk   = (const float*)d_in[6];
    const float* Wv   = (const float*)d_in[7];
    const float* Wg   = (const float*)d_in[8];
    const float* lng  = (const float*)d_in[9];
    const float* lnb  = (const float*)d_in[10];
    const float* Wz   = (const float*)d_in[11];
    const float* Wo   = (const float*)d_in[12];
    float* out = (float*)d_out;

    char* ws = (char*)d_ws;
    const size_t qk_bytes = (size_t)B_ * H_ * N_ * HDP_ * 2;       // 4 MiB each
    unsigned short* qp = (unsigned short*)ws;  ws += qk_bytes;
    unsigned short* kp = (unsigned short*)ws;  ws += qk_bytes;
    unsigned short* vT = (unsigned short*)ws;  ws += (size_t)B_ * H_ * HD_ * N_ * 2;
    float* gbuf = (float*)ws;                  ws += (size_t)B_ * N_ * D_ * 4;
    unsigned short* bias = (unsigned short*)ws; ws += (size_t)B_ * H_ * N_ * N_ * 2;
    float* obuf = (float*)ws;                  ws += (size_t)B_ * N_ * D_ * 4;
    unsigned short* Xhi = (unsigned short*)ws; ws += (size_t)B_ * N_ * D_ * 2;
    unsigned short* Xlo = (unsigned short*)ws; ws += (size_t)B_ * N_ * D_ * 2;
    unsigned short* Whi = (unsigned short*)ws; ws += (size_t)D_ * D_ * 2;
    unsigned short* Wlo = (unsigned short*)ws; ws += (size_t)D_ * D_ * 2;

    // zero hd padding of q/k (they are adjacent)
    hipMemsetAsync(qp, 0, qk_bytes * 2, stream);

    proj_kernel<<<dim3(32, 12, 4), 256, 0, stream>>>(
        node, kin, Wq, bq, Wk, Wv, Wg, qp, kp, vT, gbuf);
    bias_kernel<<<dim3(32768), 256, 0, stream>>>(edge, lng, lnb, Wz, bias);
    attn_kernel<<<dim3(2048), 64, 0, stream>>>(qp, kp, vT, bias, mask, obuf);
    prep_kernel<<<dim3(6144, 2), 256, 0, stream>>>(gbuf, obuf, Wo, Xhi, Xlo, Whi, Wlo);
    out_gemm<<<dim3(32, 12), 256, 0, stream>>>(Xhi, Xlo, Whi, Wlo, out);
}